// Round 2
// baseline (867.737 us; speedup 1.0000x reference)
//
#include <hip/hip_runtime.h>
#include <hip/hip_bf16.h>

typedef __bf16 bf16x8 __attribute__((ext_vector_type(8)));
typedef float  f32x4  __attribute__((ext_vector_type(4)));

#define B_SZ   2
#define T_SEQ  2048
#define C_EMB  2048
#define NH     16
#define HD     128
#define M_ROWS (B_SZ * T_SEQ)   /* 4096 */
#define N_QKV  (3 * C_EMB)      /* 6144 */

static __device__ __forceinline__ unsigned short f2b(float f) {
  union { __hip_bfloat16 h; unsigned short u; } cv;
  cv.h = __float2bfloat16(f);
  return cv.u;
}

static __device__ __forceinline__ void store_out(float* p, float v) { *p = v; }
static __device__ __forceinline__ void store_out(unsigned short* p, float v) { *p = f2b(v); }

// load 4 consecutive elements as bf16 (convert if fp32 source)
static __device__ __forceinline__ ushort4 load4_bf16(const float* p) {
  float4 v = *(const float4*)p;
  ushort4 o;
  o.x = f2b(v.x); o.y = f2b(v.y); o.z = f2b(v.z); o.w = f2b(v.w);
  return o;
}
static __device__ __forceinline__ ushort4 load4_bf16(const unsigned short* p) {
  return *(const ushort4*)p;
}

// ---------------------------------------------------------------------------
// C[M,N] = A[M,K] (row-major, lda) * B[K,N] (row-major, ldb) + bias[N]
// A: fp32 or bf16 (template). B: fp32, transposed+converted through LDS.
// 128x128 tile, BK=32, 4 waves (2x2), 16x16x32 bf16 MFMA, fp32 accum.
// No global_load_lds, no pre-transpose — correctness-first structure.
// ---------------------------------------------------------------------------
template <typename AT, typename OutT>
__global__ __launch_bounds__(256) void gemm_any(const AT* __restrict__ A, int lda,
                                                const float* __restrict__ B, int ldb,
                                                const float* __restrict__ bias,
                                                OutT* __restrict__ C, int ldc,
                                                int M, int N, int K) {
  __shared__ __align__(16) unsigned short As[128 * 32];   // [m][k]
  __shared__ __align__(16) unsigned short Bs[128 * 32];   // [n][k], k-groups XOR-swizzled by (n&3)
  __shared__ __align__(16) float Bstage[32 * 132];        // fp32 [k][n+pad]

  const int tid = threadIdx.x;
  const int wave = tid >> 6, lane = tid & 63;
  const int wm = wave >> 1, wn = wave & 1;
  const int ln = lane & 15, lq = lane >> 4;
  const int bm0 = blockIdx.y * 128, bn0 = blockIdx.x * 128;

  f32x4 acc[4][4];
  #pragma unroll
  for (int i = 0; i < 4; ++i)
    #pragma unroll
    for (int j = 0; j < 4; ++j) acc[i][j] = (f32x4){0.f, 0.f, 0.f, 0.f};

  for (int k0 = 0; k0 < K; k0 += 32) {
    // ---- stage A: global (AT) -> bf16 LDS [m][k], coalesced, ds_write_b64
    #pragma unroll
    for (int j = 0; j < 4; ++j) {
      const int item = tid + j * 256;        // 0..1023
      const int m = item >> 3;               // 0..127
      const int kf = (item & 7) * 4;         // 0,4,..,28
      ushort4 h4 = load4_bf16(A + (size_t)(bm0 + m) * lda + k0 + kf);
      *(ushort4*)(As + m * 32 + kf) = h4;
    }
    // ---- stage B step 1: global fp32 -> LDS fp32 [k][n], coalesced b128
    #pragma unroll
    for (int j = 0; j < 4; ++j) {
      const int item = tid + j * 256;
      const int kr = item >> 5;              // 0..31
      const int nf = (item & 31) * 4;        // 0,4,..,124
      *(float4*)(Bstage + kr * 132 + nf) =
          *(const float4*)(B + (size_t)(k0 + kr) * ldb + bn0 + nf);
    }
    __syncthreads();
    // ---- stage B step 2: transpose+convert -> bf16 [n][k] (swizzled groups)
    #pragma unroll
    for (int j = 0; j < 4; ++j) {
      const int item = tid + j * 256;
      const int n = item >> 3;               // 0..127
      const int kq = item & 7;               // 0..7 (4-k chunk)
      const int k = kq * 4;
      ushort4 h4;
      h4.x = f2b(Bstage[(k + 0) * 132 + n]);
      h4.y = f2b(Bstage[(k + 1) * 132 + n]);
      h4.z = f2b(Bstage[(k + 2) * 132 + n]);
      h4.w = f2b(Bstage[(k + 3) * 132 + n]);
      *(ushort4*)(Bs + n * 32 + (((kq >> 1) ^ (n & 3)) << 3) + ((kq & 1) << 2)) = h4;
    }
    __syncthreads();
    // ---- fragments + MFMA
    bf16x8 af[4], bfv[4];
    #pragma unroll
    for (int i = 0; i < 4; ++i) {
      af[i] = *(const bf16x8*)(As + (wm * 64 + i * 16 + ln) * 32 + lq * 8);
      const int n = wn * 64 + i * 16 + ln;
      bfv[i] = *(const bf16x8*)(Bs + n * 32 + ((lq ^ (n & 3)) << 3));
    }
    #pragma unroll
    for (int i = 0; i < 4; ++i)
      #pragma unroll
      for (int j = 0; j < 4; ++j)
        acc[i][j] = __builtin_amdgcn_mfma_f32_16x16x32_bf16(af[i], bfv[j], acc[i][j], 0, 0, 0);
    __syncthreads();  // protect As/Bstage/Bs before next iteration's writes
  }

  #pragma unroll
  for (int i = 0; i < 4; ++i) {
    const int row0 = bm0 + wm * 64 + i * 16 + lq * 4;
    #pragma unroll
    for (int j = 0; j < 4; ++j) {
      const int col = bn0 + wn * 64 + j * 16 + ln;
      const float bv = bias[col];
      #pragma unroll
      for (int r = 0; r < 4; ++r)
        store_out(&C[(size_t)(row0 + r) * ldc + col], acc[i][j][r] + bv);
    }
  }
}

// ---------------------------------------------------------------------------
// Flash attention. grid: (T/64, NH, B). Block 256 = 4 waves; wave w owns
// queries [w*16, w*16+16). qkv is bf16 [B*T, 6144]. y is written back into
// the q-columns of qkv (race-free: each block's writes hit only cells that
// only itself reads, and it reads them into LDS before any write).
// ---------------------------------------------------------------------------
__global__ __launch_bounds__(256) void attn_flash(unsigned short* __restrict__ qkv) {
  __shared__ __align__(16) unsigned short Qs[64 * 136];
  __shared__ __align__(16) unsigned short Ks[64 * 136];
  __shared__ __align__(16) unsigned short VTs[128 * 72];  // V^T: [d][key]
  __shared__ __align__(16) unsigned short Ps[64 * 72];    // P:   [q][key]

  const int tid = threadIdx.x;
  const int w = tid >> 6, lane = tid & 63;
  const int ln = lane & 15, lq = lane >> 4;
  const int qb0 = blockIdx.x * 64;
  const int h = blockIdx.y;
  const int b = blockIdx.z;
  const float SCALE = 0.08838834764831845f;  // 1/sqrt(128)

  // stage Q (64 rows x 128 d)
  #pragma unroll
  for (int j = 0; j < 4; ++j) {
    int s = tid + j * 256;
    int row = s >> 4, c8 = s & 15;
    uint4 v = *(const uint4*)(qkv + (size_t)(b * T_SEQ + qb0 + row) * N_QKV + h * HD + c8 * 8);
    *(uint4*)(Qs + row * 136 + c8 * 8) = v;
  }
  __syncthreads();

  bf16x8 aq[4];
  #pragma unroll
  for (int ks = 0; ks < 4; ++ks)
    aq[ks] = *(const bf16x8*)(Qs + (w * 16 + ln) * 136 + ks * 32 + lq * 8);

  f32x4 oacc[8];
  #pragma unroll
  for (int dt = 0; dt < 8; ++dt) oacc[dt] = (f32x4){0.f, 0.f, 0.f, 0.f};
  float m_i[4] = {-1e30f, -1e30f, -1e30f, -1e30f};
  float l_i[4] = {0.f, 0.f, 0.f, 0.f};

  const int nkb = qb0 / 64 + 1;  // causal
  for (int kb = 0; kb < nkb; ++kb) {
    __syncthreads();
    #pragma unroll
    for (int j = 0; j < 4; ++j) {
      int s = tid + j * 256;
      int row = s >> 4, c8 = s & 15;
      size_t gbase = (size_t)(b * T_SEQ + kb * 64 + row) * N_QKV + h * HD + c8 * 8;
      uint4 kvv = *(const uint4*)(qkv + gbase + C_EMB);
      *(uint4*)(Ks + row * 136 + c8 * 8) = kvv;
      union { uint4 u; unsigned short hh[8]; } cv;
      cv.u = *(const uint4*)(qkv + gbase + 2 * C_EMB);
      #pragma unroll
      for (int i = 0; i < 8; ++i)
        VTs[(c8 * 8 + i) * 72 + row] = cv.hh[i];
    }
    __syncthreads();

    // S = Q K^T
    f32x4 sacc[4];
    #pragma unroll
    for (int nt = 0; nt < 4; ++nt) sacc[nt] = (f32x4){0.f, 0.f, 0.f, 0.f};
    #pragma unroll
    for (int ks = 0; ks < 4; ++ks)
      #pragma unroll
      for (int nt = 0; nt < 4; ++nt) {
        bf16x8 bk = *(const bf16x8*)(Ks + (nt * 16 + ln) * 136 + ks * 32 + lq * 8);
        sacc[nt] = __builtin_amdgcn_mfma_f32_16x16x32_bf16(aq[ks], bk, sacc[nt], 0, 0, 0);
      }

    // online softmax; D-layout: row = lq*4 + r (query), col = ln (key)
    float sv[4][4], alpha[4];
    #pragma unroll
    for (int r = 0; r < 4; ++r) {
      const int qg = qb0 + w * 16 + lq * 4 + r;
      float rm = -1e30f;
      #pragma unroll
      for (int nt = 0; nt < 4; ++nt) {
        const int kg = kb * 64 + nt * 16 + ln;
        float s = sacc[nt][r] * SCALE;
        if (kg > qg) s = -1e30f;
        sv[nt][r] = s;
        rm = fmaxf(rm, s);
      }
      rm = fmaxf(rm, __shfl_xor(rm, 1));
      rm = fmaxf(rm, __shfl_xor(rm, 2));
      rm = fmaxf(rm, __shfl_xor(rm, 4));
      rm = fmaxf(rm, __shfl_xor(rm, 8));
      const float mnew = fmaxf(m_i[r], rm);
      const float a = __expf(m_i[r] - mnew);
      alpha[r] = a;
      m_i[r] = mnew;
      float ps = 0.f;
      #pragma unroll
      for (int nt = 0; nt < 4; ++nt) {
        float p = __expf(sv[nt][r] - mnew);
        sv[nt][r] = p;
        ps += p;
      }
      ps += __shfl_xor(ps, 1);
      ps += __shfl_xor(ps, 2);
      ps += __shfl_xor(ps, 4);
      ps += __shfl_xor(ps, 8);
      l_i[r] = l_i[r] * a + ps;
    }
    #pragma unroll
    for (int dt = 0; dt < 8; ++dt)
      #pragma unroll
      for (int r = 0; r < 4; ++r) oacc[dt][r] *= alpha[r];

    // P -> LDS (D-layout -> A-layout); wave touches only its own 16 rows
    #pragma unroll
    for (int nt = 0; nt < 4; ++nt)
      #pragma unroll
      for (int r = 0; r < 4; ++r)
        Ps[(w * 16 + lq * 4 + r) * 72 + nt * 16 + ln] = f2b(sv[nt][r]);

    // O += P V
    #pragma unroll
    for (int ks2 = 0; ks2 < 2; ++ks2) {
      bf16x8 ap = *(const bf16x8*)(Ps + (w * 16 + ln) * 72 + ks2 * 32 + lq * 8);
      #pragma unroll
      for (int dt = 0; dt < 8; ++dt) {
        bf16x8 bv = *(const bf16x8*)(VTs + (dt * 16 + ln) * 72 + ks2 * 32 + lq * 8);
        oacc[dt] = __builtin_amdgcn_mfma_f32_16x16x32_bf16(ap, bv, oacc[dt], 0, 0, 0);
      }
    }
  }

  // write y into the q-columns of qkv (alias; see header comment)
  #pragma unroll
  for (int r = 0; r < 4; ++r) {
    const float inv = 1.f / l_i[r];
    const int qg = qb0 + w * 16 + lq * 4 + r;
    #pragma unroll
    for (int dt = 0; dt < 8; ++dt)
      qkv[(size_t)(b * T_SEQ + qg) * N_QKV + h * HD + dt * 16 + ln] = f2b(oacc[dt][r] * inv);
  }
}

// ---------------------------------------------------------------- launch
extern "C" void kernel_launch(void* const* d_in, const int* in_sizes, int n_in,
                              void* d_out, int out_size, void* d_ws, size_t ws_size,
                              hipStream_t stream) {
  (void)in_sizes; (void)n_in; (void)out_size; (void)ws_size;
  const float* x      = (const float*)d_in[0];
  const float* W_attn = (const float*)d_in[1];
  const float* b_attn = (const float*)d_in[2];
  const float* W_proj = (const float*)d_in[3];
  const float* b_proj = (const float*)d_in[4];
  float* out = (float*)d_out;

  // workspace: ONLY qkv bf16 [4096 x 6144] = 48 MiB
  unsigned short* qkv = (unsigned short*)d_ws;

  // qkv = x @ W_attn + b_attn   (fp32 in, bf16 out)
  gemm_any<float, unsigned short><<<dim3(N_QKV / 128, M_ROWS / 128), 256, 0, stream>>>(
      x, C_EMB, W_attn, N_QKV, b_attn, qkv, N_QKV, M_ROWS, N_QKV, C_EMB);

  // attention; y written into q-columns of qkv
  attn_flash<<<dim3(T_SEQ / 64, NH, B_SZ), 256, 0, stream>>>(qkv);

  // out = y @ W_proj + b_proj   (bf16 A strided in qkv, fp32 out)
  gemm_any<unsigned short, float><<<dim3(C_EMB / 128, M_ROWS / 128), 256, 0, stream>>>(
      qkv, N_QKV, W_proj, C_EMB, b_proj, out, C_EMB, M_ROWS, C_EMB, C_EMB);
}

// Round 3
// 808.298 us; speedup vs baseline: 1.0735x; 1.0735x over previous
//
#include <hip/hip_runtime.h>
#include <hip/hip_bf16.h>

typedef __bf16 bf16x8 __attribute__((ext_vector_type(8)));
typedef float  f32x4  __attribute__((ext_vector_type(4)));

#define B_SZ   2
#define T_SEQ  2048
#define C_EMB  2048
#define NH     16
#define HD     128
#define M_ROWS (B_SZ * T_SEQ)   /* 4096 */
#define N_QKV  (3 * C_EMB)      /* 6144 */
#define LQK    (2 * C_EMB)      /* 4096: qk buffer row length (q|k columns) */

static __device__ __forceinline__ unsigned short f2b(float f) {
  union { __hip_bfloat16 h; unsigned short u; } cv;
  cv.h = __float2bfloat16(f);
  return cv.u;
}
static __device__ __forceinline__ void store_out(float* p, float v) { *p = v; }
static __device__ __forceinline__ void store_out(unsigned short* p, float v) { *p = f2b(v); }

static __device__ __forceinline__ ushort4 load4_bf16(const float* p) {
  float4 v = *(const float4*)p;
  ushort4 o; o.x = f2b(v.x); o.y = f2b(v.y); o.z = f2b(v.z); o.w = f2b(v.w);
  return o;
}
static __device__ __forceinline__ ushort4 load4_bf16(const unsigned short* p) {
  return *(const ushort4*)p;
}

// async global->LDS, 16B/lane; LDS dest must be wave-uniform base + lane*16
static __device__ __forceinline__ void async_cp16(const unsigned short* g, unsigned short* l) {
  __builtin_amdgcn_global_load_lds((__attribute__((address_space(1))) void*)(g),
                                   (__attribute__((address_space(3))) void*)(l), 16, 0, 0);
}

// ---------------------------------------------------------------------------
// Shared epilogue. MODE 0: C[row][col] = acc + bias (OutT).
// MODE 1 (qkv split): cols [0,4096) -> qk bf16 (row-major, ld 4096);
//                     cols [4096,6144) -> vt bf16 [(b*NH+h)*HD+d][t]  (V^T).
// ---------------------------------------------------------------------------
template <int MODE, typename OutT>
static __device__ __forceinline__ void gemm_epilogue(
    f32x4 (&acc)[4][4], const float* __restrict__ bias,
    OutT* __restrict__ C, int ldc,
    unsigned short* __restrict__ qk, unsigned short* __restrict__ vt,
    int bm0, int bn0, int wm, int wn, int ln, int lq) {
  #pragma unroll
  for (int i = 0; i < 4; ++i) {
    const int row0 = bm0 + wm * 64 + i * 16 + lq * 4;
    #pragma unroll
    for (int j = 0; j < 4; ++j) {
      const int col = bn0 + wn * 64 + j * 16 + ln;
      const float bv = bias[col];
      if constexpr (MODE == 0) {
        #pragma unroll
        for (int r = 0; r < 4; ++r)
          store_out(&C[(size_t)(row0 + r) * ldc + col], acc[i][j][r] + bv);
      } else {
        if (bn0 < 2 * C_EMB) {  // q or k columns (wave-uniform per block)
          #pragma unroll
          for (int r = 0; r < 4; ++r)
            qk[(size_t)(row0 + r) * LQK + col] = f2b(acc[i][j][r] + bv);
        } else {                // v columns -> transposed store
          const int c2 = col - 2 * C_EMB;           // h*128 + d
          const int bb = row0 >> 11;                // batch (block rows stay in one batch)
          const int t0 = row0 & (T_SEQ - 1);
          const int vrow = (bb * NH + (c2 >> 7)) * HD + (c2 & 127);
          ushort4 p;
          p.x = f2b(acc[i][j][0] + bv); p.y = f2b(acc[i][j][1] + bv);
          p.z = f2b(acc[i][j][2] + bv); p.w = f2b(acc[i][j][3] + bv);
          *(ushort4*)(vt + (size_t)vrow * T_SEQ + t0) = p;  // t0 % 4 == 0 -> 8B aligned
        }
      }
    }
  }
}

// ---------------------------------------------------------------------------
// Tier A GEMM (m97 structure): C = A[M,K](bf16, lda) * Bt[N,K]^T(bf16) + bias.
// global_load_lds width-16 staging, 128x128 tile, BK=32.
// ---------------------------------------------------------------------------
template <int MODE, typename OutT>
__global__ __launch_bounds__(256) void gemm_bt(const unsigned short* __restrict__ A, int lda,
                                               const unsigned short* __restrict__ Bt,
                                               const float* __restrict__ bias,
                                               OutT* __restrict__ C, int ldc,
                                               unsigned short* __restrict__ qk,
                                               unsigned short* __restrict__ vt,
                                               int N, int K) {
  __shared__ __align__(16) unsigned short As[128 * 32];
  __shared__ __align__(16) unsigned short Bs[128 * 32];
  const int tid = threadIdx.x;
  const int wave = tid >> 6, lane = tid & 63;
  const int wm = wave >> 1, wn = wave & 1;
  const int ln = lane & 15, lq = lane >> 4;
  const int bm0 = blockIdx.y * 128, bn0 = blockIdx.x * 128;

  f32x4 acc[4][4];
  #pragma unroll
  for (int i = 0; i < 4; ++i)
    #pragma unroll
    for (int j = 0; j < 4; ++j) acc[i][j] = (f32x4){0.f, 0.f, 0.f, 0.f};

  // per-lane staging addresses; LDS side is wave-uniform base + lane*16B
  const unsigned short* Ag = A  + (size_t)(bm0 + wave * 32 + (lane >> 2)) * lda + (lane & 3) * 8;
  const unsigned short* Bg = Bt + (size_t)(bn0 + wave * 32 + (lane >> 2)) * K   + (lane & 3) * 8;
  unsigned short* Al = As + wave * 1024 + lane * 8;
  unsigned short* Bl = Bs + wave * 1024 + lane * 8;

  for (int k0 = 0; k0 < K; k0 += 32) {
    async_cp16(Ag + k0, Al);
    async_cp16(Ag + k0 + 16 * lda, Al + 512);
    async_cp16(Bg + k0, Bl);
    async_cp16(Bg + k0 + 16 * K, Bl + 512);
    __syncthreads();
    bf16x8 af[4], bfv[4];
    #pragma unroll
    for (int i = 0; i < 4; ++i) {
      af[i]  = *(const bf16x8*)(As + (wm * 64 + i * 16 + ln) * 32 + lq * 8);
      bfv[i] = *(const bf16x8*)(Bs + (wn * 64 + i * 16 + ln) * 32 + lq * 8);
    }
    #pragma unroll
    for (int i = 0; i < 4; ++i)
      #pragma unroll
      for (int j = 0; j < 4; ++j)
        acc[i][j] = __builtin_amdgcn_mfma_f32_16x16x32_bf16(af[i], bfv[j], acc[i][j], 0, 0, 0);
    __syncthreads();
  }
  gemm_epilogue<MODE, OutT>(acc, bias, C, ldc, qk, vt, bm0, bn0, wm, wn, ln, lq);
}

// ---------------------------------------------------------------------------
// Tier B GEMM (validated round-2 structure): A fp32/bf16, B fp32 [K,N],
// B transposed+converted through LDS per tile.
// ---------------------------------------------------------------------------
template <int MODE, typename AT, typename OutT>
__global__ __launch_bounds__(256) void gemm_any(const AT* __restrict__ A, int lda,
                                                const float* __restrict__ B, int ldb,
                                                const float* __restrict__ bias,
                                                OutT* __restrict__ C, int ldc,
                                                unsigned short* __restrict__ qk,
                                                unsigned short* __restrict__ vt,
                                                int N, int K) {
  __shared__ __align__(16) unsigned short As[128 * 32];
  __shared__ __align__(16) unsigned short Bs[128 * 32];
  __shared__ __align__(16) float Bstage[32 * 132];

  const int tid = threadIdx.x;
  const int wave = tid >> 6, lane = tid & 63;
  const int wm = wave >> 1, wn = wave & 1;
  const int ln = lane & 15, lq = lane >> 4;
  const int bm0 = blockIdx.y * 128, bn0 = blockIdx.x * 128;

  f32x4 acc[4][4];
  #pragma unroll
  for (int i = 0; i < 4; ++i)
    #pragma unroll
    for (int j = 0; j < 4; ++j) acc[i][j] = (f32x4){0.f, 0.f, 0.f, 0.f};

  for (int k0 = 0; k0 < K; k0 += 32) {
    #pragma unroll
    for (int j = 0; j < 4; ++j) {
      const int item = tid + j * 256;
      const int m = item >> 3;
      const int kf = (item & 7) * 4;
      *(ushort4*)(As + m * 32 + kf) = load4_bf16(A + (size_t)(bm0 + m) * lda + k0 + kf);
    }
    #pragma unroll
    for (int j = 0; j < 4; ++j) {
      const int item = tid + j * 256;
      const int kr = item >> 5;
      const int nf = (item & 31) * 4;
      *(float4*)(Bstage + kr * 132 + nf) =
          *(const float4*)(B + (size_t)(k0 + kr) * ldb + bn0 + nf);
    }
    __syncthreads();
    #pragma unroll
    for (int j = 0; j < 4; ++j) {
      const int item = tid + j * 256;
      const int n = item >> 3;
      const int kq = item & 7;
      const int k = kq * 4;
      ushort4 h4;
      h4.x = f2b(Bstage[(k + 0) * 132 + n]);
      h4.y = f2b(Bstage[(k + 1) * 132 + n]);
      h4.z = f2b(Bstage[(k + 2) * 132 + n]);
      h4.w = f2b(Bstage[(k + 3) * 132 + n]);
      *(ushort4*)(Bs + n * 32 + (((kq >> 1) ^ (n & 3)) << 3) + ((kq & 1) << 2)) = h4;
    }
    __syncthreads();
    bf16x8 af[4], bfv[4];
    #pragma unroll
    for (int i = 0; i < 4; ++i) {
      af[i] = *(const bf16x8*)(As + (wm * 64 + i * 16 + ln) * 32 + lq * 8);
      const int n = wn * 64 + i * 16 + ln;
      bfv[i] = *(const bf16x8*)(Bs + n * 32 + ((lq ^ (n & 3)) << 3));
    }
    #pragma unroll
    for (int i = 0; i < 4; ++i)
      #pragma unroll
      for (int j = 0; j < 4; ++j)
        acc[i][j] = __builtin_amdgcn_mfma_f32_16x16x32_bf16(af[i], bfv[j], acc[i][j], 0, 0, 0);
    __syncthreads();
  }
  gemm_epilogue<MODE, OutT>(acc, bias, C, ldc, qk, vt, bm0, bn0, wm, wn, ln, lq);
}

// ---------------------------------------------------------------- prep (Tier A)
__global__ __launch_bounds__(256) void cast_x_bf16(const float4* __restrict__ in,
                                                   ushort4* __restrict__ out, int n4) {
  int i = blockIdx.x * 256 + threadIdx.x;
  if (i < n4) {
    float4 v = in[i];
    ushort4 o; o.x = f2b(v.x); o.y = f2b(v.y); o.z = f2b(v.z); o.w = f2b(v.w);
    out[i] = o;
  }
}

// out[n][k] = (bf16) in[k][n]
__global__ __launch_bounds__(256) void transpose_cast(const float* __restrict__ in,
                                                      unsigned short* __restrict__ out,
                                                      int R, int Cc) {
  __shared__ float t[32][33];
  const int bx = blockIdx.x * 32, by = blockIdx.y * 32;
  const int tx = threadIdx.x & 31, ty = threadIdx.x >> 5;
  #pragma unroll
  for (int j = 0; j < 32; j += 8)
    t[ty + j][tx] = in[(size_t)(by + ty + j) * Cc + bx + tx];
  __syncthreads();
  #pragma unroll
  for (int j = 0; j < 32; j += 8)
    out[(size_t)(bx + ty + j) * R + by + tx] = f2b(t[tx][ty + j]);
}

// ---------------------------------------------------------------------------
// Barrier-free flash attention.
// grid (32, NH, B), block 256 = 4 waves; wave w owns queries [qb0+w*16, +16).
// Q,K read from qk (bf16, ld 4096; k at col offset 2048); V^T read from vt.
// MFMA fragments load DIRECTLY from global (L2-resident) — no LDS staging,
// no __syncthreads. LDS only for the per-wave-private P D->A round-trip.
// y written into the q-columns of qk (disjoint from all K/V reads; own Q is
// in registers before the loop).
// ---------------------------------------------------------------------------
__global__ __launch_bounds__(256) void attn_bfree(unsigned short* __restrict__ qk,
                                                  const unsigned short* __restrict__ vt) {
  __shared__ __align__(16) unsigned short Ps[64 * 72];  // per-wave 16-row slices

  const int tid = threadIdx.x;
  const int w = tid >> 6, lane = tid & 63;
  const int ln = lane & 15, lq = lane >> 4;
  // long blocks first + long/short pairing for load balance
  const int bx = blockIdx.x;
  const int qbi = (bx & 1) ? (bx >> 1) : (31 - (bx >> 1));
  const int qb0 = qbi * 64;
  const int h = blockIdx.y, b = blockIdx.z;
  const float SCALE = 0.08838834764831845f;  // 1/sqrt(128)

  // Q fragments straight from global
  const unsigned short* Qp = qk + (size_t)(b * T_SEQ + qb0 + w * 16 + ln) * LQK + h * HD + lq * 8;
  bf16x8 aq[4];
  #pragma unroll
  for (int ks = 0; ks < 4; ++ks) aq[ks] = *(const bf16x8*)(Qp + ks * 32);

  // per-lane K / V^T base pointers
  const unsigned short* Kp = qk + (size_t)b * T_SEQ * LQK + (size_t)ln * LQK + C_EMB + h * HD + lq * 8;
  const unsigned short* Vp = vt + ((size_t)(b * NH + h) * HD + ln) * T_SEQ + lq * 8;

  f32x4 oacc[8];
  #pragma unroll
  for (int dt = 0; dt < 8; ++dt) oacc[dt] = (f32x4){0.f, 0.f, 0.f, 0.f};
  float m_i[4] = {-1e30f, -1e30f, -1e30f, -1e30f};
  float l_i[4] = {0.f, 0.f, 0.f, 0.f};

  const int nkb = qbi + 1;
  for (int kb = 0; kb < nkb; ++kb) {
    // ---- S = Q K^T : B-fragments direct from global
    const unsigned short* Kkb = Kp + (size_t)(kb * 64) * LQK;
    f32x4 sacc[4];
    #pragma unroll
    for (int nt = 0; nt < 4; ++nt) {
      sacc[nt] = (f32x4){0.f, 0.f, 0.f, 0.f};
      const unsigned short* Kt = Kkb + (size_t)(nt * 16) * LQK;
      #pragma unroll
      for (int ks = 0; ks < 4; ++ks) {
        bf16x8 bk = *(const bf16x8*)(Kt + ks * 32);
        sacc[nt] = __builtin_amdgcn_mfma_f32_16x16x32_bf16(aq[ks], bk, sacc[nt], 0, 0, 0);
      }
    }

    // ---- online softmax (D-layout: row = lq*4+r, col = ln within n-tile)
    const bool diag = (kb * 64 + 63 > qb0 + w * 16);  // wave-uniform mask skip
    float sv[4][4], alpha[4];
    #pragma unroll
    for (int r = 0; r < 4; ++r) {
      const int qg = qb0 + w * 16 + lq * 4 + r;
      float rm = -1e30f;
      #pragma unroll
      for (int nt = 0; nt < 4; ++nt) {
        float s = sacc[nt][r] * SCALE;
        if (diag) {
          const int kg = kb * 64 + nt * 16 + ln;
          if (kg > qg) s = -1e30f;
        }
        sv[nt][r] = s;
        rm = fmaxf(rm, s);
      }
      rm = fmaxf(rm, __shfl_xor(rm, 1));
      rm = fmaxf(rm, __shfl_xor(rm, 2));
      rm = fmaxf(rm, __shfl_xor(rm, 4));
      rm = fmaxf(rm, __shfl_xor(rm, 8));
      const float mnew = fmaxf(m_i[r], rm);
      const float a = __expf(m_i[r] - mnew);
      alpha[r] = a;
      m_i[r] = mnew;
      float ps = 0.f;
      #pragma unroll
      for (int nt = 0; nt < 4; ++nt) {
        float p = __expf(sv[nt][r] - mnew);
        sv[nt][r] = p;
        ps += p;
      }
      ps += __shfl_xor(ps, 1);
      ps += __shfl_xor(ps, 2);
      ps += __shfl_xor(ps, 4);
      ps += __shfl_xor(ps, 8);
      l_i[r] = l_i[r] * a + ps;
    }
    #pragma unroll
    for (int dt = 0; dt < 8; ++dt)
      #pragma unroll
      for (int r = 0; r < 4; ++r) oacc[dt][r] *= alpha[r];

    // ---- P D->A layout round-trip (wave-private rows; no barrier needed)
    #pragma unroll
    for (int nt = 0; nt < 4; ++nt)
      #pragma unroll
      for (int r = 0; r < 4; ++r)
        Ps[(w * 16 + lq * 4 + r) * 72 + nt * 16 + ln] = f2b(sv[nt][r]);

    // ---- O += P V : V^T B-fragments direct from global
    #pragma unroll
    for (int ks2 = 0; ks2 < 2; ++ks2) {
      bf16x8 ap = *(const bf16x8*)(Ps + (w * 16 + ln) * 72 + ks2 * 32 + lq * 8);
      #pragma unroll
      for (int dt = 0; dt < 8; ++dt) {
        bf16x8 bv = *(const bf16x8*)(Vp + (size_t)(dt * 16) * T_SEQ + kb * 64 + ks2 * 32);
        oacc[dt] = __builtin_amdgcn_mfma_f32_16x16x32_bf16(ap, bv, oacc[dt], 0, 0, 0);
      }
    }
  }

  // write y into the q-columns of qk
  #pragma unroll
  for (int r = 0; r < 4; ++r) {
    const float inv = 1.f / l_i[r];
    const int qg = qb0 + w * 16 + lq * 4 + r;
    #pragma unroll
    for (int dt = 0; dt < 8; ++dt)
      qk[(size_t)(b * T_SEQ + qg) * LQK + h * HD + dt * 16 + ln] = f2b(oacc[dt][r] * inv);
  }
}

// ---------------------------------------------------------------- launch
extern "C" void kernel_launch(void* const* d_in, const int* in_sizes, int n_in,
                              void* d_out, int out_size, void* d_ws, size_t ws_size,
                              hipStream_t stream) {
  (void)in_sizes; (void)n_in; (void)out_size;
  const float* x      = (const float*)d_in[0];
  const float* W_attn = (const float*)d_in[1];
  const float* b_attn = (const float*)d_in[2];
  const float* W_proj = (const float*)d_in[3];
  const float* b_proj = (const float*)d_in[4];
  float* out = (float*)d_out;

  char* ws = (char*)d_ws;
  unsigned short* qk = (unsigned short*)(ws);                  // 32 MiB [4096][4096]
  unsigned short* vt = (unsigned short*)(ws + 33554432);       // 16 MiB [B*NH*HD][T]
  // Tier A extras (only touched if ws_size permits):
  unsigned short* xb  = (unsigned short*)(ws + 50331648);      // 16 MiB x bf16
  unsigned short* WaT = (unsigned short*)(ws + 67108864);      // 24 MiB W_attn^T bf16
  unsigned short* WpT = (unsigned short*)(ws + 92274688);      // 8  MiB W_proj^T bf16
  const bool tierA = (ws_size >= 100663296);                   // 96 MiB

  if (tierA) {
    const int n_x = M_ROWS * C_EMB;
    cast_x_bf16<<<n_x / 4 / 256, 256, 0, stream>>>((const float4*)x, (ushort4*)xb, n_x / 4);
    transpose_cast<<<dim3(N_QKV / 32, C_EMB / 32), 256, 0, stream>>>(W_attn, WaT, C_EMB, N_QKV);
    transpose_cast<<<dim3(C_EMB / 32, C_EMB / 32), 256, 0, stream>>>(W_proj, WpT, C_EMB, C_EMB);
    gemm_bt<1, unsigned short><<<dim3(N_QKV / 128, M_ROWS / 128), 256, 0, stream>>>(
        xb, C_EMB, WaT, b_attn, (unsigned short*)nullptr, 0, qk, vt, N_QKV, C_EMB);
  } else {
    gemm_any<1, float, unsigned short><<<dim3(N_QKV / 128, M_ROWS / 128), 256, 0, stream>>>(
        x, C_EMB, W_attn, N_QKV, b_attn, (unsigned short*)nullptr, 0, qk, vt, N_QKV, C_EMB);
  }

  attn_bfree<<<dim3(32, NH, B_SZ), 256, 0, stream>>>(qk, vt);

  if (tierA) {
    gemm_bt<0, float><<<dim3(C_EMB / 128, M_ROWS / 128), 256, 0, stream>>>(
        qk, LQK, WpT, b_proj, out, C_EMB, nullptr, nullptr, C_EMB, C_EMB);
  } else {
    gemm_any<0, unsigned short, float><<<dim3(C_EMB / 128, M_ROWS / 128), 256, 0, stream>>>(
        qk, LQK, W_proj, C_EMB, b_proj, out, C_EMB, nullptr, nullptr, C_EMB, C_EMB);
  }
}

// Round 4
// 489.153 us; speedup vs baseline: 1.7740x; 1.6524x over previous
//
#include <hip/hip_runtime.h>
#include <hip/hip_bf16.h>

typedef __bf16 bf16x8 __attribute__((ext_vector_type(8)));
typedef float  f32x4  __attribute__((ext_vector_type(4)));
typedef short  short4v __attribute__((ext_vector_type(4)));

#define B_SZ   2
#define T_SEQ  2048
#define C_EMB  2048
#define NH     16
#define HD     128
#define M_ROWS (B_SZ * T_SEQ)   /* 4096 */
#define N_QKV  (3 * C_EMB)      /* 6144 */
#define LQK    (2 * C_EMB)      /* 4096: qk buffer row length (q|k columns) */

static __device__ __forceinline__ unsigned short f2b(float f) {
  union { __hip_bfloat16 h; unsigned short u; } cv;
  cv.h = __float2bfloat16(f);
  return cv.u;
}
static __device__ __forceinline__ void store_out(float* p, float v) { *p = v; }
static __device__ __forceinline__ void store_out(unsigned short* p, float v) { *p = f2b(v); }

static __device__ __forceinline__ ushort4 load4_bf16(const float* p) {
  float4 v = *(const float4*)p;
  ushort4 o; o.x = f2b(v.x); o.y = f2b(v.y); o.z = f2b(v.z); o.w = f2b(v.w);
  return o;
}
static __device__ __forceinline__ ushort4 load4_bf16(const unsigned short* p) {
  return *(const ushort4*)p;
}

// async global->LDS, 16B/lane; LDS dest must be wave-uniform base + lane*16
static __device__ __forceinline__ void async_cp16(const unsigned short* g, unsigned short* l) {
  __builtin_amdgcn_global_load_lds((__attribute__((address_space(1))) void*)(g),
                                   (__attribute__((address_space(3))) void*)(l), 16, 0, 0);
}

// ---------------------------------------------------------------------------
// Shared epilogue. MODE 0: C[row][col] = acc + bias (OutT).
// MODE 1 (qkv split): cols [0,4096) -> qk bf16 (row-major, ld 4096);
//                     cols [4096,6144) -> vt bf16 [(b*NH+h)*HD+d][t]  (V^T).
// ---------------------------------------------------------------------------
template <int MODE, typename OutT>
static __device__ __forceinline__ void gemm_epilogue(
    f32x4 (&acc)[4][4], const float* __restrict__ bias,
    OutT* __restrict__ C, int ldc,
    unsigned short* __restrict__ qk, unsigned short* __restrict__ vt,
    int bm0, int bn0, int wm, int wn, int ln, int lq) {
  #pragma unroll
  for (int i = 0; i < 4; ++i) {
    const int row0 = bm0 + wm * 64 + i * 16 + lq * 4;
    #pragma unroll
    for (int j = 0; j < 4; ++j) {
      const int col = bn0 + wn * 64 + j * 16 + ln;
      const float bv = bias[col];
      if constexpr (MODE == 0) {
        #pragma unroll
        for (int r = 0; r < 4; ++r)
          store_out(&C[(size_t)(row0 + r) * ldc + col], acc[i][j][r] + bv);
      } else {
        if (bn0 < 2 * C_EMB) {  // q or k columns (wave-uniform per block)
          #pragma unroll
          for (int r = 0; r < 4; ++r)
            qk[(size_t)(row0 + r) * LQK + col] = f2b(acc[i][j][r] + bv);
        } else {                // v columns -> transposed store
          const int c2 = col - 2 * C_EMB;           // h*128 + d
          const int bb = row0 >> 11;                // batch
          const int t0 = row0 & (T_SEQ - 1);
          const int vrow = (bb * NH + (c2 >> 7)) * HD + (c2 & 127);
          ushort4 p;
          p.x = f2b(acc[i][j][0] + bv); p.y = f2b(acc[i][j][1] + bv);
          p.z = f2b(acc[i][j][2] + bv); p.w = f2b(acc[i][j][3] + bv);
          *(ushort4*)(vt + (size_t)vrow * T_SEQ + t0) = p;  // t0 % 4 == 0
        }
      }
    }
  }
}

// ---------------------------------------------------------------------------
// Tier A GEMM (m97 structure): C = A[M,K](bf16, lda) * Bt[N,K]^T(bf16) + bias.
// ---------------------------------------------------------------------------
template <int MODE, typename OutT>
__global__ __launch_bounds__(256) void gemm_bt(const unsigned short* __restrict__ A, int lda,
                                               const unsigned short* __restrict__ Bt,
                                               const float* __restrict__ bias,
                                               OutT* __restrict__ C, int ldc,
                                               unsigned short* __restrict__ qk,
                                               unsigned short* __restrict__ vt,
                                               int N, int K) {
  __shared__ __align__(16) unsigned short As[128 * 32];
  __shared__ __align__(16) unsigned short Bs[128 * 32];
  const int tid = threadIdx.x;
  const int wave = tid >> 6, lane = tid & 63;
  const int wm = wave >> 1, wn = wave & 1;
  const int ln = lane & 15, lq = lane >> 4;
  const int bm0 = blockIdx.y * 128, bn0 = blockIdx.x * 128;

  f32x4 acc[4][4];
  #pragma unroll
  for (int i = 0; i < 4; ++i)
    #pragma unroll
    for (int j = 0; j < 4; ++j) acc[i][j] = (f32x4){0.f, 0.f, 0.f, 0.f};

  const unsigned short* Ag = A  + (size_t)(bm0 + wave * 32 + (lane >> 2)) * lda + (lane & 3) * 8;
  const unsigned short* Bg = Bt + (size_t)(bn0 + wave * 32 + (lane >> 2)) * K   + (lane & 3) * 8;
  unsigned short* Al = As + wave * 1024 + lane * 8;
  unsigned short* Bl = Bs + wave * 1024 + lane * 8;

  for (int k0 = 0; k0 < K; k0 += 32) {
    async_cp16(Ag + k0, Al);
    async_cp16(Ag + k0 + 16 * lda, Al + 512);
    async_cp16(Bg + k0, Bl);
    async_cp16(Bg + k0 + 16 * K, Bl + 512);
    __syncthreads();
    bf16x8 af[4], bfv[4];
    #pragma unroll
    for (int i = 0; i < 4; ++i) {
      af[i]  = *(const bf16x8*)(As + (wm * 64 + i * 16 + ln) * 32 + lq * 8);
      bfv[i] = *(const bf16x8*)(Bs + (wn * 64 + i * 16 + ln) * 32 + lq * 8);
    }
    #pragma unroll
    for (int i = 0; i < 4; ++i)
      #pragma unroll
      for (int j = 0; j < 4; ++j)
        acc[i][j] = __builtin_amdgcn_mfma_f32_16x16x32_bf16(af[i], bfv[j], acc[i][j], 0, 0, 0);
    __syncthreads();
  }
  gemm_epilogue<MODE, OutT>(acc, bias, C, ldc, qk, vt, bm0, bn0, wm, wn, ln, lq);
}

// ---------------------------------------------------------------------------
// Tier B GEMM fallback (validated round-2 structure).
// ---------------------------------------------------------------------------
template <int MODE, typename AT, typename OutT>
__global__ __launch_bounds__(256) void gemm_any(const AT* __restrict__ A, int lda,
                                                const float* __restrict__ B, int ldb,
                                                const float* __restrict__ bias,
                                                OutT* __restrict__ C, int ldc,
                                                unsigned short* __restrict__ qk,
                                                unsigned short* __restrict__ vt,
                                                int N, int K) {
  __shared__ __align__(16) unsigned short As[128 * 32];
  __shared__ __align__(16) unsigned short Bs[128 * 32];
  __shared__ __align__(16) float Bstage[32 * 132];

  const int tid = threadIdx.x;
  const int wave = tid >> 6, lane = tid & 63;
  const int wm = wave >> 1, wn = wave & 1;
  const int ln = lane & 15, lq = lane >> 4;
  const int bm0 = blockIdx.y * 128, bn0 = blockIdx.x * 128;

  f32x4 acc[4][4];
  #pragma unroll
  for (int i = 0; i < 4; ++i)
    #pragma unroll
    for (int j = 0; j < 4; ++j) acc[i][j] = (f32x4){0.f, 0.f, 0.f, 0.f};

  for (int k0 = 0; k0 < K; k0 += 32) {
    #pragma unroll
    for (int j = 0; j < 4; ++j) {
      const int item = tid + j * 256;
      const int m = item >> 3;
      const int kf = (item & 7) * 4;
      *(ushort4*)(As + m * 32 + kf) = load4_bf16(A + (size_t)(bm0 + m) * lda + k0 + kf);
    }
    #pragma unroll
    for (int j = 0; j < 4; ++j) {
      const int item = tid + j * 256;
      const int kr = item >> 5;
      const int nf = (item & 31) * 4;
      *(float4*)(Bstage + kr * 132 + nf) =
          *(const float4*)(B + (size_t)(k0 + kr) * ldb + bn0 + nf);
    }
    __syncthreads();
    #pragma unroll
    for (int j = 0; j < 4; ++j) {
      const int item = tid + j * 256;
      const int n = item >> 3;
      const int kq = item & 7;
      const int k = kq * 4;
      ushort4 h4;
      h4.x = f2b(Bstage[(k + 0) * 132 + n]);
      h4.y = f2b(Bstage[(k + 1) * 132 + n]);
      h4.z = f2b(Bstage[(k + 2) * 132 + n]);
      h4.w = f2b(Bstage[(k + 3) * 132 + n]);
      *(ushort4*)(Bs + n * 32 + (((kq >> 1) ^ (n & 3)) << 3) + ((kq & 1) << 2)) = h4;
    }
    __syncthreads();
    bf16x8 af[4], bfv[4];
    #pragma unroll
    for (int i = 0; i < 4; ++i) {
      af[i] = *(const bf16x8*)(As + (wm * 64 + i * 16 + ln) * 32 + lq * 8);
      const int n = wn * 64 + i * 16 + ln;
      bfv[i] = *(const bf16x8*)(Bs + n * 32 + ((lq ^ (n & 3)) << 3));
    }
    #pragma unroll
    for (int i = 0; i < 4; ++i)
      #pragma unroll
      for (int j = 0; j < 4; ++j)
        acc[i][j] = __builtin_amdgcn_mfma_f32_16x16x32_bf16(af[i], bfv[j], acc[i][j], 0, 0, 0);
    __syncthreads();
  }
  gemm_epilogue<MODE, OutT>(acc, bias, C, ldc, qk, vt, bm0, bn0, wm, wn, ln, lq);
}

// ---------------------------------------------------------------- prep (Tier A)
__global__ __launch_bounds__(256) void cast_x_bf16(const float4* __restrict__ in,
                                                   ushort4* __restrict__ out, int n4) {
  int i = blockIdx.x * 256 + threadIdx.x;
  if (i < n4) {
    float4 v = in[i];
    ushort4 o; o.x = f2b(v.x); o.y = f2b(v.y); o.z = f2b(v.z); o.w = f2b(v.w);
    out[i] = o;
  }
}

__global__ __launch_bounds__(256) void transpose_cast(const float* __restrict__ in,
                                                      unsigned short* __restrict__ out,
                                                      int R, int Cc) {
  __shared__ float t[32][33];
  const int bx = blockIdx.x * 32, by = blockIdx.y * 32;
  const int tx = threadIdx.x & 31, ty = threadIdx.x >> 5;
  #pragma unroll
  for (int j = 0; j < 32; j += 8)
    t[ty + j][tx] = in[(size_t)(by + ty + j) * Cc + bx + tx];
  __syncthreads();
  #pragma unroll
  for (int j = 0; j < 32; j += 8)
    out[(size_t)(bx + ty + j) * R + by + tx] = f2b(t[tx][ty + j]);
}

// ---------------------------------------------------------------------------
// Flash attention, transposed-S ("S^T") formulation.
// grid (32, NH, B), block 256 = 4 waves; wave w owns 16 queries.
// S^T = K Q^T via 16x16x32 MFMA (K from LDS, Q in regs). D-layout puts
// query in col=ln, keys in regs (lq*4+r) -> softmax max/sum are in-register
// + 2 shuffles (xor16,32); alpha/l are one scalar per lane. P^T emerges in
// exactly the B-operand layout of 16x16x16 bf16 MFMA, so PV (O^T = V^T P^T)
// consumes P straight from registers — no LDS round-trip in the chain.
// V^T comes pre-transposed from GEMM1 (vt), staged to LDS coalesced.
// Epilogue transposes O^T -> O through reused LDS (once per block).
// y written into the q-columns of qk (race-free as before).
// ---------------------------------------------------------------------------
__global__ __launch_bounds__(256, 4) void attn_st(unsigned short* __restrict__ qk,
                                                  const unsigned short* __restrict__ vt) {
  __shared__ __align__(16) unsigned short Ks[64 * 136];   // K tile [key][d], pad 136
  __shared__ __align__(16) unsigned short VTs[128 * 72];  // V^T tile [d][key], pad 72

  const int tid = threadIdx.x;
  const int w = tid >> 6, lane = tid & 63;
  const int ln = lane & 15, lq = lane >> 4;
  const int bx = blockIdx.x;
  const int qbi = (bx & 1) ? (bx >> 1) : (31 - (bx >> 1));  // long/short pairing
  const int qb0 = qbi * 64;
  const int h = blockIdx.y, b = blockIdx.z;
  const float SCALE = 0.08838834764831845f;  // 1/sqrt(128)

  // Q fragments (B-operand: n=ln=query, k=lq*8..) straight from global, once
  const int qg = qb0 + w * 16 + ln;
  const unsigned short* Qp = qk + (size_t)(b * T_SEQ + qg) * LQK + h * HD + lq * 8;
  bf16x8 bq[4];
  #pragma unroll
  for (int ks = 0; ks < 4; ++ks) bq[ks] = *(const bf16x8*)(Qp + ks * 32);

  f32x4 ot[8];  // O^T accum: dt-tile, regs = d = dt*16+lq*4+r, col = query ln
  #pragma unroll
  for (int dt = 0; dt < 8; ++dt) ot[dt] = (f32x4){0.f, 0.f, 0.f, 0.f};
  float m_i = -1e30f, l_i = 0.f;

  for (int kb = 0; kb <= qbi; ++kb) {
    __syncthreads();  // prev iter's LDS reads complete
    #pragma unroll
    for (int j = 0; j < 4; ++j) {           // K tile: 64 keys x 128 d
      const int s = tid + j * 256;
      const int row = s >> 4, c8 = s & 15;
      *(uint4*)(Ks + row * 136 + c8 * 8) =
          *(const uint4*)(qk + (size_t)(b * T_SEQ + kb * 64 + row) * LQK + C_EMB + h * HD + c8 * 8);
    }
    #pragma unroll
    for (int j = 0; j < 4; ++j) {           // V^T tile: 128 d x 64 keys
      const int s = tid + j * 256;
      const int row = s >> 3, c8 = s & 7;
      *(uint4*)(VTs + row * 72 + c8 * 8) =
          *(const uint4*)(vt + ((size_t)(b * NH + h) * HD + row) * T_SEQ + kb * 64 + c8 * 8);
    }
    __syncthreads();

    // S^T = K Q^T : 4 key-tiles (m) x 1 q-tile (n) x 4 k-steps (d)
    f32x4 st[4];
    #pragma unroll
    for (int kt = 0; kt < 4; ++kt) {
      st[kt] = (f32x4){0.f, 0.f, 0.f, 0.f};
      #pragma unroll
      for (int ks = 0; ks < 4; ++ks) {
        bf16x8 ak = *(const bf16x8*)(Ks + (kt * 16 + ln) * 136 + ks * 32 + lq * 8);
        st[kt] = __builtin_amdgcn_mfma_f32_16x16x32_bf16(ak, bq[ks], st[kt], 0, 0, 0);
      }
    }

    // scale + causal mask + online softmax (per lane: one query column)
    const bool diag = (kb * 64 + 63 > qb0 + w * 16);
    float sv[4][4];
    float rm = -1e30f;
    #pragma unroll
    for (int kt = 0; kt < 4; ++kt)
      #pragma unroll
      for (int r = 0; r < 4; ++r) {
        float s = st[kt][r] * SCALE;
        if (diag && (kb * 64 + kt * 16 + lq * 4 + r > qg)) s = -1e30f;
        sv[kt][r] = s;
        rm = fmaxf(rm, s);
      }
    rm = fmaxf(rm, __shfl_xor(rm, 16));
    rm = fmaxf(rm, __shfl_xor(rm, 32));
    const float mnew = fmaxf(m_i, rm);
    const float alpha = __expf(m_i - mnew);
    m_i = mnew;
    float ps = 0.f;
    short4v pfrag[4];
    #pragma unroll
    for (int kt = 0; kt < 4; ++kt)
      #pragma unroll
      for (int r = 0; r < 4; ++r) {
        float p = __expf(sv[kt][r] - mnew);
        ps += p;
        pfrag[kt][r] = (short)f2b(p);
      }
    ps += __shfl_xor(ps, 16);
    ps += __shfl_xor(ps, 32);
    l_i = l_i * alpha + ps;
    #pragma unroll
    for (int dt = 0; dt < 8; ++dt)
      #pragma unroll
      for (int r = 0; r < 4; ++r) ot[dt][r] *= alpha;

    // O^T += V^T P^T : 8 d-tiles x 4 key-steps, K=16 MFMA, P from registers
    #pragma unroll
    for (int kt = 0; kt < 4; ++kt)
      #pragma unroll
      for (int dt = 0; dt < 8; ++dt) {
        short4v av = *(const short4v*)(VTs + (dt * 16 + ln) * 72 + kt * 16 + lq * 4);
        ot[dt] = __builtin_amdgcn_mfma_f32_16x16x16bf16_1k(av, pfrag[kt], ot[dt], 0, 0, 0);
      }
  }

  // epilogue: O^T -> O via LDS (reuse Ks as Os[64 q][136]), then coalesced store
  __syncthreads();
  const float inv = 1.f / l_i;
  #pragma unroll
  for (int dt = 0; dt < 8; ++dt) {
    ushort4 p4;
    p4.x = f2b(ot[dt][0] * inv); p4.y = f2b(ot[dt][1] * inv);
    p4.z = f2b(ot[dt][2] * inv); p4.w = f2b(ot[dt][3] * inv);
    *(ushort4*)(Ks + (w * 16 + ln) * 136 + dt * 16 + lq * 4) = p4;
  }
  __syncthreads();
  #pragma unroll
  for (int j = 0; j < 4; ++j) {
    const int s = tid + j * 256;
    const int row = s >> 4, c8 = s & 15;
    *(uint4*)(qk + (size_t)(b * T_SEQ + qb0 + row) * LQK + h * HD + c8 * 8) =
        *(const uint4*)(Ks + row * 136 + c8 * 8);
  }
}

// ---------------------------------------------------------------- launch
extern "C" void kernel_launch(void* const* d_in, const int* in_sizes, int n_in,
                              void* d_out, int out_size, void* d_ws, size_t ws_size,
                              hipStream_t stream) {
  (void)in_sizes; (void)n_in; (void)out_size;
  const float* x      = (const float*)d_in[0];
  const float* W_attn = (const float*)d_in[1];
  const float* b_attn = (const float*)d_in[2];
  const float* W_proj = (const float*)d_in[3];
  const float* b_proj = (const float*)d_in[4];
  float* out = (float*)d_out;

  char* ws = (char*)d_ws;
  unsigned short* qk = (unsigned short*)(ws);                  // 32 MiB [4096][4096]
  unsigned short* vt = (unsigned short*)(ws + 33554432);       // 16 MiB [B*NH*HD][T]
  unsigned short* xb  = (unsigned short*)(ws + 50331648);      // 16 MiB x bf16
  unsigned short* WaT = (unsigned short*)(ws + 67108864);      // 24 MiB W_attn^T bf16
  unsigned short* WpT = (unsigned short*)(ws + 92274688);      // 8  MiB W_proj^T bf16
  const bool tierA = (ws_size >= 100663296);                   // 96 MiB

  if (tierA) {
    const int n_x = M_ROWS * C_EMB;
    cast_x_bf16<<<n_x / 4 / 256, 256, 0, stream>>>((const float4*)x, (ushort4*)xb, n_x / 4);
    transpose_cast<<<dim3(N_QKV / 32, C_EMB / 32), 256, 0, stream>>>(W_attn, WaT, C_EMB, N_QKV);
    transpose_cast<<<dim3(C_EMB / 32, C_EMB / 32), 256, 0, stream>>>(W_proj, WpT, C_EMB, C_EMB);
    gemm_bt<1, unsigned short><<<dim3(N_QKV / 128, M_ROWS / 128), 256, 0, stream>>>(
        xb, C_EMB, WaT, b_attn, (unsigned short*)nullptr, 0, qk, vt, N_QKV, C_EMB);
  } else {
    gemm_any<1, float, unsigned short><<<dim3(N_QKV / 128, M_ROWS / 128), 256, 0, stream>>>(
        x, C_EMB, W_attn, N_QKV, b_attn, (unsigned short*)nullptr, 0, qk, vt, N_QKV, C_EMB);
  }

  attn_st<<<dim3(32, NH, B_SZ), 256, 0, stream>>>(qk, vt);

  if (tierA) {
    gemm_bt<0, float><<<dim3(C_EMB / 128, M_ROWS / 128), 256, 0, stream>>>(
        qk, LQK, WpT, b_proj, out, C_EMB, nullptr, nullptr, C_EMB, C_EMB);
  } else {
    gemm_any<0, unsigned short, float><<<dim3(C_EMB / 128, M_ROWS / 128), 256, 0, stream>>>(
        qk, LQK, W_proj, C_EMB, b_proj, out, C_EMB, nullptr, nullptr, C_EMB, C_EMB);
  }
}